// Round 7
// baseline (48.362 us; speedup 1.0000x reference)
//
#include <hip/hip_runtime.h>

// Problem constants (from reference): H=64, EH=128, B=512, T=512
#define B_  512
#define T_  512
#define H_  64
#define EH_ 128   // 2*H
#define NW  8     // waves per block (512 threads)
#define NG  32    // partial groups per block (NW * 4)

typedef const __attribute__((address_space(1))) unsigned int GUI;
typedef __attribute__((address_space(3))) unsigned int LUI;

__device__ __forceinline__ float sigm(float x) { return 1.0f / (1.0f + __expf(-x)); }

__device__ __forceinline__ float dot8(const float4& a1, const float4& a2,
                                      const float4& b1, const float4& b2) {
  return a1.x * b1.x + a1.y * b1.y + a1.z * b1.z + a1.w * b1.w
       + a2.x * b2.x + a2.y * b2.y + a2.z * b2.z + a2.w * b2.w;
}

__global__ __launch_bounds__(512, 4)
void attn_decoder_fused(const float* __restrict__ h0, const float* __restrict__ c0,
                        const float* __restrict__ enc,
                        const float* __restrict__ Wa,  const float* __restrict__ ba,
                        const float* __restrict__ Wc,  const float* __restrict__ bc,
                        const float* __restrict__ wif, const float* __restrict__ whf,
                        const float* __restrict__ bif, const float* __restrict__ bhf,
                        const float* __restrict__ wir, const float* __restrict__ whr,
                        const float* __restrict__ bir, const float* __restrict__ bhr,
                        const int* __restrict__ dip,
                        float* __restrict__ out)
{
  const int b    = blockIdx.x;
  const int tid  = threadIdx.x;
  const int lane = tid & 63;
  const int wv   = tid >> 6;    // 0..7
  const int grp  = lane >> 4;   // 0..3  (row within chunk)
  const int gl   = lane & 15;   // 0..15 (column group: 16 lanes per row)

  // per-wave 3-slot LDS ring: 3 x 2KB = 6KB per wave, 48KB per block
  __shared__ __align__(16) float s_tiles[NW * 1536];
  __shared__ float s_l[NG];
  __shared__ float s_acc[NG][EH_];      // 16 KB
  __shared__ float s_cat[2 * EH_];
  __shared__ float s_part[4][H_];
  __shared__ float s_comb[H_];
  __shared__ float s_h0[2 * H_];
  __shared__ float s_gates[2][4 * H_];

  const float* encb = enc + (size_t)b * T_ * EH_;
  char* wtile = (char*)s_tiles + wv * 6144;   // wave-uniform

  // this lane's 8 attention-weight columns (dec-hidden half of W_attn + bias
  // cancel in the softmax -> never computed)
  const float4 w1 = *(const float4*)(&Wa[4 * gl]);
  const float4 w2 = *(const float4*)(&Wa[64 + 4 * gl]);

  // Stage chunk c (4 rows = 2KB) into ring slot at byte offset so.
  // LDS dest is linear (wave-uniform base + lane*16); the XOR row-swizzle is
  // applied on the GLOBAL source address (m173 pattern):
  //   LDS 16B-slot (r_local, c4) holds enc[r][c4 ^ r_local].
  // Within-row XOR of bits 0-1 stays inside 64B sectors -> coalescing intact.
  auto stage = [&](int c, int so) {
    const int rl0 = lane >> 5;          // 0/1
    const int c4  = lane & 31;          // 16B granule within row
    const int r0  = wv * 64 + c * 4;
    const float* s0 = encb + (size_t)(r0 + rl0) * EH_ + ((c4 ^ rl0) << 2);
    const float* s1 = encb + (size_t)(r0 + 2 + rl0) * EH_ + ((c4 ^ (2 + rl0)) << 2);
    __builtin_amdgcn_global_load_lds((GUI*)s0, (LUI*)(wtile + so), 16, 0, 0);
    __builtin_amdgcn_global_load_lds((GUI*)s1, (LUI*)(wtile + so + 1024), 16, 0, 0);
  };

  float  l = 0.0f;
  float4 acc1 = {0.f, 0.f, 0.f, 0.f}, acc2 = {0.f, 0.f, 0.f, 0.f};

  // prologue: 3 chunks in flight (6 load-instrs)
  stage(0, 0); stage(1, 2048); stage(2, 4096);

  const int rdoff = grp * 512 + ((gl ^ grp) << 4);   // swizzled read offset

#define CHUNK_BODY(SO)                                                      \
  {                                                                         \
    float4 e1 = *(const float4*)(wtile + (SO) + rdoff);                     \
    float4 e2 = *(const float4*)(wtile + (SO) + rdoff + 256);               \
    float s = dot8(e1, e2, w1, w2);                                         \
    _Pragma("unroll")                                                       \
    for (int off = 8; off; off >>= 1) s += __shfl_xor(s, off, 64);          \
    float p = __expf(s);                                                    \
    l += p;                                                                 \
    acc1.x += p * e1.x; acc1.y += p * e1.y;                                 \
    acc1.z += p * e1.z; acc1.w += p * e1.w;                                 \
    acc2.x += p * e2.x; acc2.y += p * e2.y;                                 \
    acc2.z += p * e2.z; acc2.w += p * e2.w;                                 \
  }

  // main loop: counted vmcnt(4) keeps 2 chunks in flight; lgkmcnt(0) fences
  // the ring-3 slot reuse (stage(c+3) overwrites the slot just read).
  int so = 0;
  for (int c = 0; c < 13; ++c) {
    asm volatile("s_waitcnt vmcnt(4)" ::: "memory");
    float4 e1 = *(const float4*)(wtile + so + rdoff);
    float4 e2 = *(const float4*)(wtile + so + rdoff + 256);
    asm volatile("s_waitcnt lgkmcnt(0)" ::: "memory");
    stage(c + 3, so);
    float s = dot8(e1, e2, w1, w2);
#pragma unroll
    for (int off = 8; off; off >>= 1) s += __shfl_xor(s, off, 64);
    float p = __expf(s);
    l += p;
    acc1.x += p * e1.x; acc1.y += p * e1.y;
    acc1.z += p * e1.z; acc1.w += p * e1.w;
    acc2.x += p * e2.x; acc2.y += p * e2.y;
    acc2.z += p * e2.z; acc2.w += p * e2.w;
    so += 2048; if (so == 6144) so = 0;
  }
  // tail: chunks 13 (slot 2048), 14 (slot 4096), 15 (slot 0)
  asm volatile("s_waitcnt vmcnt(4)" ::: "memory");
  CHUNK_BODY(2048)
  asm volatile("s_waitcnt vmcnt(2)" ::: "memory");
  CHUNK_BODY(4096)
  asm volatile("s_waitcnt vmcnt(0)" ::: "memory");
  CHUNK_BODY(0)

  // stash group-partial state: group g = wv*4 + grp (rows == grp mod 4)
  const int g = wv * 4 + grp;
  *(float4*)(&s_acc[g][4 * gl])      = acc1;
  *(float4*)(&s_acc[g][64 + 4 * gl]) = acc2;
  if (gl == 0) s_l[g] = l;
  __syncthreads();

  const int di = dip[0];

  // merge 32 partial states (plain sums) and build out_cat in LDS
  if (tid < EH_) {
    float L = 0.0f, a = 0.0f;
#pragma unroll
    for (int w = 0; w < NG; ++w) {
      L += s_l[w];
      a += s_acc[w][tid];
    }
    s_cat[EH_ + tid] = a / L;                        // attn_applied
    s_cat[tid]       = encb[(size_t)di * EH_ + tid]; // enc[b, di, :]
  } else if (tid < 2 * EH_) {
    int j = tid - EH_;                               // 0..127
    s_h0[j] = h0[(j >> 6) * B_ * H_ + b * H_ + (j & 63)];
  }
  __syncthreads();

  // comb = relu(out_cat @ Wc^T + bc) : 64 outputs, 256-dot each, 4-way split
  if (tid < 256) {
    int k = tid & 63, part = tid >> 6;
    const float4* wrow = (const float4*)(Wc + k * 256 + part * 64);
    const float4* cat  = (const float4*)(s_cat + part * 64);
    float a = 0.0f;
#pragma unroll
    for (int j = 0; j < 16; ++j) {
      float4 w = wrow[j], c = cat[j];
      a += w.x * c.x + w.y * c.y + w.z * c.z + w.w * c.w;
    }
    s_part[part][k] = a;
  }
  __syncthreads();
  if (tid < H_) {
    float a = s_part[0][tid] + s_part[1][tid] + s_part[2][tid] + s_part[3][tid] + bc[tid];
    s_comb[tid] = fmaxf(a, 0.0f);
  }
  __syncthreads();

  // gates: 512 threads, one gate each: dir = tid>>8, g = tid&255
  {
    int dir = tid >> 8, gg = tid & 255;
    const float* wih = dir ? wir : wif;
    const float* whh = dir ? whr : whf;
    const float* bih = dir ? bir : bif;
    const float* bhh = dir ? bhr : bhf;
    float a = bih[gg] + bhh[gg];
    const float4* wi = (const float4*)(wih + gg * H_);
    const float4* wh = (const float4*)(whh + gg * H_);
    const float4* cm = (const float4*)(s_comb);
    const float4* hh = (const float4*)(s_h0 + dir * H_);
#pragma unroll
    for (int j = 0; j < 16; ++j) {
      float4 a1 = wi[j], x1 = cm[j];
      float4 a2 = wh[j], x2 = hh[j];
      a += a1.x * x1.x + a1.y * x1.y + a1.z * x1.z + a1.w * x1.w
         + a2.x * x2.x + a2.y * x2.y + a2.z * x2.z + a2.w * x2.w;
    }
    s_gates[dir][gg] = a;
  }
  __syncthreads();

  // finalize LSTM + write all three outputs
  if (tid < 2 * H_) {
    int dir = tid >> 6, j = tid & 63;
    float gi = s_gates[dir][j];
    float gf = s_gates[dir][H_ + j];
    float gg = s_gates[dir][2 * H_ + j];
    float go = s_gates[dir][3 * H_ + j];
    float cp = c0[dir * B_ * H_ + b * H_ + j];
    float cn = sigm(gf) * cp + sigm(gi) * tanhf(gg);
    float hn = sigm(go) * tanhf(cn);
    out[b * 2 * H_ + dir * H_ + j]                    = hn;  // output (b,1,128)
    out[B_ * 2 * H_ + dir * B_ * H_ + b * H_ + j]     = hn;  // h_new (2,b,64)
    out[2 * B_ * 2 * H_ + dir * B_ * H_ + b * H_ + j] = cn;  // c_new (2,b,64)
  }
}

extern "C" void kernel_launch(void* const* d_in, const int* in_sizes, int n_in,
                              void* d_out, int out_size, void* d_ws, size_t ws_size,
                              hipStream_t stream) {
  const float* h0  = (const float*)d_in[0];
  const float* c0  = (const float*)d_in[1];
  const float* enc = (const float*)d_in[2];
  const float* Wa  = (const float*)d_in[3];
  const float* ba  = (const float*)d_in[4];
  const float* Wc  = (const float*)d_in[5];
  const float* bc  = (const float*)d_in[6];
  const float* wif = (const float*)d_in[7];
  const float* whf = (const float*)d_in[8];
  const float* bif = (const float*)d_in[9];
  const float* bhf = (const float*)d_in[10];
  const float* wir = (const float*)d_in[11];
  const float* whr = (const float*)d_in[12];
  const float* bir = (const float*)d_in[13];
  const float* bhr = (const float*)d_in[14];
  const int*   dip = (const int*)d_in[15];
  float* out = (float*)d_out;

  attn_decoder_fused<<<B_, 512, 0, stream>>>(h0, c0, enc, Wa, ba, Wc, bc,
                                             wif, whf, bif, bhf,
                                             wir, whr, bir, bhr, dip, out);
}

// Round 8
// 34.106 us; speedup vs baseline: 1.4180x; 1.4180x over previous
//
#include <hip/hip_runtime.h>

// Problem constants (from reference): H=64, EH=128, B=512, T=512
#define B_  512
#define T_  512
#define H_  64
#define EH_ 128   // 2*H
#define NW  8     // waves per block (512 threads)
#define NG  32    // partial groups per block (NW * 4)

__device__ __forceinline__ float sigm(float x) { return 1.0f / (1.0f + __expf(-x)); }

__device__ __forceinline__ float dot4(const float4& a, const float4& b) {
  return a.x * b.x + a.y * b.y + a.z * b.z + a.w * b.w;
}
__device__ __forceinline__ float dot8(const float4& a1, const float4& a2,
                                      const float4& b1, const float4& b2) {
  return dot4(a1, b1) + dot4(a2, b2);
}

__global__ __launch_bounds__(512, 4)
void attn_decoder_fused(const float* __restrict__ h0, const float* __restrict__ c0,
                        const float* __restrict__ enc,
                        const float* __restrict__ Wa,  const float* __restrict__ ba,
                        const float* __restrict__ Wc,  const float* __restrict__ bc,
                        const float* __restrict__ wif, const float* __restrict__ whf,
                        const float* __restrict__ bif, const float* __restrict__ bhf,
                        const float* __restrict__ wir, const float* __restrict__ whr,
                        const float* __restrict__ bir, const float* __restrict__ bhr,
                        const int* __restrict__ dip,
                        float* __restrict__ out)
{
  const int b    = blockIdx.x;
  const int tid  = threadIdx.x;
  const int lane = tid & 63;
  const int wv   = tid >> 6;    // 0..7
  const int grp  = lane >> 4;   // 0..3  (row within quad)
  const int gl   = lane & 15;   // 0..15 (column group: 16 lanes per row)

  __shared__ float s_l[NG];
  __shared__ float s_acc[NG][EH_];      // 16 KB
  __shared__ float s_cat[2 * EH_];      // [enc[b,di,:], attn_applied]
  __shared__ float s_comb[H_];
  __shared__ float s_h0[2 * H_];
  __shared__ float s_gates[2][4 * H_];

  const float* encb = enc + (size_t)b * T_ * EH_;

  // this lane's 8 attention-weight columns (dec-hidden half of W_attn + bias
  // cancel in the softmax -> never computed)
  const float4 w1 = *(const float4*)(&Wa[4 * gl]);
  const float4 w2 = *(const float4*)(&Wa[64 + 4 * gl]);

  float  l = 0.0f;
  float4 acc1 = {0.f, 0.f, 0.f, 0.f}, acc2 = {0.f, 0.f, 0.f, 0.f};

  const float* rb = encb + (size_t)(wv * 64 + grp) * EH_ + 4 * gl;

  // ---- attention: proven quad geometry, additive (no-max) online softmax ----
#pragma unroll 1
  for (int it = 0; it < 4; ++it) {
    const float* p0 = rb + (size_t)(it * 16) * EH_;
    float4 eA1 = *(const float4*)(p0);
    float4 eA2 = *(const float4*)(p0 + 64);
    float4 eB1 = *(const float4*)(p0 + 4 * EH_);
    float4 eB2 = *(const float4*)(p0 + 4 * EH_ + 64);
    float4 eC1 = *(const float4*)(p0 + 8 * EH_);
    float4 eC2 = *(const float4*)(p0 + 8 * EH_ + 64);
    float4 eD1 = *(const float4*)(p0 + 12 * EH_);
    float4 eD2 = *(const float4*)(p0 + 12 * EH_ + 64);

    float sA = dot8(eA1, eA2, w1, w2);
    float sB = dot8(eB1, eB2, w1, w2);
    float sC = dot8(eC1, eC2, w1, w2);
    float sD = dot8(eD1, eD2, w1, w2);
#pragma unroll
    for (int off = 8; off; off >>= 1) {
      sA += __shfl_xor(sA, off, 64);
      sB += __shfl_xor(sB, off, 64);
      sC += __shfl_xor(sC, off, 64);
      sD += __shfl_xor(sD, off, 64);
    }
    float pA = __expf(sA), pB = __expf(sB);
    float pC = __expf(sC), pD = __expf(sD);
    l += pA + pB + pC + pD;
    acc1.x += pA * eA1.x + pB * eB1.x + pC * eC1.x + pD * eD1.x;
    acc1.y += pA * eA1.y + pB * eB1.y + pC * eC1.y + pD * eD1.y;
    acc1.z += pA * eA1.z + pB * eB1.z + pC * eC1.z + pD * eD1.z;
    acc1.w += pA * eA1.w + pB * eB1.w + pC * eC1.w + pD * eD1.w;
    acc2.x += pA * eA2.x + pB * eB2.x + pC * eC2.x + pD * eD2.x;
    acc2.y += pA * eA2.y + pB * eB2.y + pC * eC2.y + pD * eD2.y;
    acc2.z += pA * eA2.z + pB * eB2.z + pC * eC2.z + pD * eD2.z;
    acc2.w += pA * eA2.w + pB * eB2.w + pC * eC2.w + pD * eD2.w;
  }

  const int g = wv * 4 + grp;   // partial-group id 0..31
  *(float4*)(&s_acc[g][4 * gl])      = acc1;
  *(float4*)(&s_acc[g][64 + 4 * gl]) = acc2;
  if (gl == 0) s_l[g] = l;
  __syncthreads();

  const int di = dip[0];

  // ---- merge 32 partial states (plain sums); build cat + h0 in LDS ----
  if (tid < EH_) {
    float L = 0.0f, a = 0.0f;
#pragma unroll
    for (int w = 0; w < NG; ++w) { L += s_l[w]; a += s_acc[w][tid]; }
    s_cat[EH_ + tid] = a / L;                        // attn_applied
    s_cat[tid]       = encb[(size_t)di * EH_ + tid]; // enc[b, di, :]
  } else if (tid < 2 * EH_) {
    int j = tid - EH_;
    s_h0[j] = h0[(j >> 6) * B_ * H_ + b * H_ + (j & 63)];
  }
  __syncthreads();

  // ---- comb = relu(cat @ Wc^T + bc): coalesced, one Wc row per wave-instr ----
  // wave wv handles rows [wv*8, wv*8+8); lane covers cols 4*lane..4*lane+3.
  {
    float4 c4 = *(const float4*)(&s_cat[4 * lane]);
#pragma unroll
    for (int batch = 0; batch < 2; ++batch) {
      const int r0 = wv * 8 + batch * 4;
      float sA = dot4(*(const float4*)(Wc + (r0 + 0) * 256 + 4 * lane), c4);
      float sB = dot4(*(const float4*)(Wc + (r0 + 1) * 256 + 4 * lane), c4);
      float sC = dot4(*(const float4*)(Wc + (r0 + 2) * 256 + 4 * lane), c4);
      float sD = dot4(*(const float4*)(Wc + (r0 + 3) * 256 + 4 * lane), c4);
#pragma unroll
      for (int off = 32; off; off >>= 1) {
        sA += __shfl_xor(sA, off, 64);
        sB += __shfl_xor(sB, off, 64);
        sC += __shfl_xor(sC, off, 64);
        sD += __shfl_xor(sD, off, 64);
      }
      if (lane < 4) {
        int r = r0 + lane;
        float v = (lane == 0) ? sA : (lane == 1) ? sB : (lane == 2) ? sC : sD;
        s_comb[r] = fmaxf(v + bc[r], 0.0f);
      }
    }
  }
  __syncthreads();

  // ---- gates: coalesced quad geometry; dir is wave-uniform ----
  // wave wv: dir = wv>>2, gates [(wv&3)*64, +64). 4 rows per wave-instr.
  {
    const int dir   = wv >> 2;
    const int gbase = (wv & 3) * 64;
    const float* wih = dir ? wir : wif;
    const float* whh = dir ? whr : whf;
    const float* bih = dir ? bir : bif;
    const float* bhh = dir ? bhr : bhf;
    float4 cm4 = *(const float4*)(&s_comb[4 * gl]);
    float4 h4  = *(const float4*)(&s_h0[dir * H_ + 4 * gl]);
#pragma unroll
    for (int batch = 0; batch < 4; ++batch) {
      const int r0 = gbase + batch * 16;   // 16 gate rows this step
      float sA = dot4(*(const float4*)(wih + (r0 +  0 + grp) * H_ + 4 * gl), cm4)
               + dot4(*(const float4*)(whh + (r0 +  0 + grp) * H_ + 4 * gl), h4);
      float sB = dot4(*(const float4*)(wih + (r0 +  4 + grp) * H_ + 4 * gl), cm4)
               + dot4(*(const float4*)(whh + (r0 +  4 + grp) * H_ + 4 * gl), h4);
      float sC = dot4(*(const float4*)(wih + (r0 +  8 + grp) * H_ + 4 * gl), cm4)
               + dot4(*(const float4*)(whh + (r0 +  8 + grp) * H_ + 4 * gl), h4);
      float sD = dot4(*(const float4*)(wih + (r0 + 12 + grp) * H_ + 4 * gl), cm4)
               + dot4(*(const float4*)(whh + (r0 + 12 + grp) * H_ + 4 * gl), h4);
#pragma unroll
      for (int off = 8; off; off >>= 1) {
        sA += __shfl_xor(sA, off, 64);
        sB += __shfl_xor(sB, off, 64);
        sC += __shfl_xor(sC, off, 64);
        sD += __shfl_xor(sD, off, 64);
      }
      if (gl < 4) {   // lane gl writes value gl for its grp
        int gg = r0 + gl * 4 + grp;
        float v = (gl == 0) ? sA : (gl == 1) ? sB : (gl == 2) ? sC : sD;
        s_gates[dir][gg] = v + bih[gg] + bhh[gg];
      }
    }
  }
  __syncthreads();

  // ---- finalize LSTM + write all three outputs ----
  if (tid < 2 * H_) {
    int dir = tid >> 6, j = tid & 63;
    float gi = s_gates[dir][j];
    float gf = s_gates[dir][H_ + j];
    float gg = s_gates[dir][2 * H_ + j];
    float go = s_gates[dir][3 * H_ + j];
    float cp = c0[dir * B_ * H_ + b * H_ + j];
    float cn = sigm(gf) * cp + sigm(gi) * tanhf(gg);
    float hn = sigm(go) * tanhf(cn);
    out[b * 2 * H_ + dir * H_ + j]                    = hn;  // output (b,1,128)
    out[B_ * 2 * H_ + dir * B_ * H_ + b * H_ + j]     = hn;  // h_new (2,b,64)
    out[2 * B_ * 2 * H_ + dir * B_ * H_ + b * H_ + j] = cn;  // c_new (2,b,64)
  }
}

extern "C" void kernel_launch(void* const* d_in, const int* in_sizes, int n_in,
                              void* d_out, int out_size, void* d_ws, size_t ws_size,
                              hipStream_t stream) {
  const float* h0  = (const float*)d_in[0];
  const float* c0  = (const float*)d_in[1];
  const float* enc = (const float*)d_in[2];
  const float* Wa  = (const float*)d_in[3];
  const float* ba  = (const float*)d_in[4];
  const float* Wc  = (const float*)d_in[5];
  const float* bc  = (const float*)d_in[6];
  const float* wif = (const float*)d_in[7];
  const float* whf = (const float*)d_in[8];
  const float* bif = (const float*)d_in[9];
  const float* bhf = (const float*)d_in[10];
  const float* wir = (const float*)d_in[11];
  const float* whr = (const float*)d_in[12];
  const float* bir = (const float*)d_in[13];
  const float* bhr = (const float*)d_in[14];
  const int*   dip = (const int*)d_in[15];
  float* out = (float*)d_out;

  attn_decoder_fused<<<B_, 512, 0, stream>>>(h0, c0, enc, Wa, ba, Wc, bc,
                                             wif, whf, bif, bhf,
                                             wir, whr, bir, bhr, dip, out);
}